// Round 1
// baseline (1404.469 us; speedup 1.0000x reference)
//
#include <hip/hip_runtime.h>
#include <cstddef>

// ---------------------------------------------------------------------------
// GCN pipeline (fp32 baseline):
//   deg/dinv -> CSR build -> GEMM1 -> AGG1(+relu) -> GEMM2 -> AGG2 -> pool -> proj
// Sizes: N=50000 nodes, E=800000 edges, F=H=512, G=64 graphs, OUT=8.
// ---------------------------------------------------------------------------

#define GEMM_BM 128
#define GEMM_BN 128
#define GEMM_BK 16

// C[M,N] = A[M,K] @ B[K,N], fp32, row-major. N,K multiples of 128/16; M guarded.
__global__ __launch_bounds__(256) void gemm_f32_kernel(
    const float* __restrict__ A, const float* __restrict__ B,
    float* __restrict__ C, int M, int N, int K)
{
    __shared__ float As[GEMM_BK][GEMM_BM + 4];  // +4 keeps float4 alignment (stride 132*4B)
    __shared__ float Bs[GEMM_BK][GEMM_BN];
    const int tid = threadIdx.x;
    const int tx = tid & 15;
    const int ty = tid >> 4;
    const int m0 = blockIdx.y * GEMM_BM;
    const int n0 = blockIdx.x * GEMM_BN;

    float acc[8][8];
#pragma unroll
    for (int i = 0; i < 8; ++i)
#pragma unroll
        for (int j = 0; j < 8; ++j) acc[i][j] = 0.f;

    for (int k0 = 0; k0 < K; k0 += GEMM_BK) {
        // stage A (transposed into LDS): 128 rows x 16 k
#pragma unroll
        for (int l = 0; l < 2; ++l) {
            int id = tid + l * 256;
            int row = id >> 2;
            int ks = (id & 3) << 2;
            float4 v = make_float4(0.f, 0.f, 0.f, 0.f);
            int gr = m0 + row;
            if (gr < M) v = *(const float4*)(A + (size_t)gr * K + k0 + ks);
            As[ks + 0][row] = v.x;
            As[ks + 1][row] = v.y;
            As[ks + 2][row] = v.z;
            As[ks + 3][row] = v.w;
        }
        // stage B: 16 k x 128 n
#pragma unroll
        for (int l = 0; l < 2; ++l) {
            int id = tid + l * 256;
            int kr = id >> 5;
            int ns = (id & 31) << 2;
            *(float4*)&Bs[kr][ns] = *(const float4*)(B + (size_t)(k0 + kr) * N + n0 + ns);
        }
        __syncthreads();
#pragma unroll
        for (int kk = 0; kk < GEMM_BK; ++kk) {
            float4 a0 = *(const float4*)&As[kk][ty << 2];
            float4 a1 = *(const float4*)&As[kk][64 + (ty << 2)];
            float4 b0 = *(const float4*)&Bs[kk][tx << 2];
            float4 b1 = *(const float4*)&Bs[kk][64 + (tx << 2)];
            float a[8] = {a0.x, a0.y, a0.z, a0.w, a1.x, a1.y, a1.z, a1.w};
            float b[8] = {b0.x, b0.y, b0.z, b0.w, b1.x, b1.y, b1.z, b1.w};
#pragma unroll
            for (int i = 0; i < 8; ++i)
#pragma unroll
                for (int j = 0; j < 8; ++j)
                    acc[i][j] = fmaf(a[i], b[j], acc[i][j]);
        }
        __syncthreads();
    }
#pragma unroll
    for (int i = 0; i < 8; ++i) {
        int r = (i < 4) ? (ty * 4 + i) : (64 + ty * 4 + (i - 4));
        int gr = m0 + r;
        if (gr >= M) continue;
        float4 c0 = make_float4(acc[i][0], acc[i][1], acc[i][2], acc[i][3]);
        float4 c1 = make_float4(acc[i][4], acc[i][5], acc[i][6], acc[i][7]);
        *(float4*)(C + (size_t)gr * N + n0 + tx * 4) = c0;
        *(float4*)(C + (size_t)gr * N + n0 + 64 + tx * 4) = c1;
    }
}

// deg += ew scattered by dst; cnt[dst]++ (for CSR)
__global__ void deg_cnt_kernel(const int* __restrict__ dst, const float* __restrict__ ew,
                               float* __restrict__ deg, int* __restrict__ cnt, int E)
{
    int e = blockIdx.x * blockDim.x + threadIdx.x;
    if (e >= E) return;
    int d = dst[e];
    atomicAdd(&deg[d], ew[e]);
    atomicAdd(&cnt[d], 1);
}

// in-place: deg[i] -> rsqrt(deg[i] + 1)   (self-loop weight 1)
__global__ void dinv_kernel(float* __restrict__ deg, int Nn)
{
    int i = blockIdx.x * blockDim.x + threadIdx.x;
    if (i >= Nn) return;
    deg[i] = rsqrtf(deg[i] + 1.0f);
}

// single-block exclusive scan of cnt[0..Nn) -> rowptr[0..Nn]
__global__ __launch_bounds__(1024) void scan_kernel(
    const int* __restrict__ cnt, int* __restrict__ rowptr, int Nn)
{
    __shared__ int tmp[1024];
    __shared__ int carry_s;
    const int tid = threadIdx.x;
    if (tid == 0) carry_s = 0;
    __syncthreads();
    const int nchunks = (Nn + 1023) / 1024;
    for (int ch = 0; ch < nchunks; ++ch) {
        const int idx = ch * 1024 + tid;
        const int v = (idx < Nn) ? cnt[idx] : 0;
        tmp[tid] = v;
        __syncthreads();
        for (int off = 1; off < 1024; off <<= 1) {
            int y = 0;
            if (tid >= off) y = tmp[tid - off];
            __syncthreads();
            if (tid >= off) tmp[tid] += y;
            __syncthreads();
        }
        const int incl = tmp[tid];
        const int c = carry_s;
        if (idx < Nn) rowptr[idx] = c + incl - v;
        __syncthreads();
        if (tid == 1023) carry_s = c + tmp[1023];
        __syncthreads();
    }
    if (tid == 0) rowptr[Nn] = carry_s;
}

// scatter edges into CSR slots; norm = dinv[s]*ew*dinv[d]
__global__ void fill_csr_kernel(const int* __restrict__ src, const int* __restrict__ dst,
                                const float* __restrict__ ew, const float* __restrict__ dinv,
                                const int* __restrict__ rowptr, int* __restrict__ cur,
                                int* __restrict__ csr_src, float* __restrict__ csr_norm, int E)
{
    int e = blockIdx.x * blockDim.x + threadIdx.x;
    if (e >= E) return;
    int s = src[e];
    int d = dst[e];
    float nrm = dinv[s] * ew[e] * dinv[d];
    int p = rowptr[d] + atomicAdd(&cur[d], 1);
    csr_src[p] = s;
    csr_norm[p] = nrm;
}

// out[n,:] = bias + dinv[n]^2 * hw[n,:] + sum_{e in CSR[n]} norm_e * hw[src_e,:]; optional relu
// block = 128 threads, each handles 4 consecutive cols (H=512)
template <int RELU>
__global__ __launch_bounds__(128) void agg_kernel(
    const float* __restrict__ hw, const float* __restrict__ dinv,
    const int* __restrict__ rowptr, const int* __restrict__ csr_src,
    const float* __restrict__ csr_norm, const float* __restrict__ bias,
    float* __restrict__ outp)
{
    const int n = blockIdx.x;
    const int c = threadIdx.x * 4;
    const float di = dinv[n];
    float4 acc = *(const float4*)(bias + c);
    {
        const float s = di * di;
        const float4 hv = *(const float4*)(hw + (size_t)n * 512 + c);
        acc.x = fmaf(s, hv.x, acc.x);
        acc.y = fmaf(s, hv.y, acc.y);
        acc.z = fmaf(s, hv.z, acc.z);
        acc.w = fmaf(s, hv.w, acc.w);
    }
    const int beg = rowptr[n];
    const int end = rowptr[n + 1];
    for (int i = beg; i < end; ++i) {
        const int s = csr_src[i];
        const float nr = csr_norm[i];
        const float4 v = *(const float4*)(hw + (size_t)s * 512 + c);
        acc.x = fmaf(nr, v.x, acc.x);
        acc.y = fmaf(nr, v.y, acc.y);
        acc.z = fmaf(nr, v.z, acc.z);
        acc.w = fmaf(nr, v.w, acc.w);
    }
    if (RELU) {
        acc.x = fmaxf(acc.x, 0.f);
        acc.y = fmaxf(acc.y, 0.f);
        acc.z = fmaxf(acc.z, 0.f);
        acc.w = fmaxf(acc.w, 0.f);
    }
    *(float4*)(outp + (size_t)n * 512 + c) = acc;
}

// batch is sorted: accumulate runs locally, atomics only at graph boundaries.
// block = 128 threads (4 cols each); each block covers 64 consecutive nodes.
__global__ __launch_bounds__(128) void pool_kernel(
    const float* __restrict__ h, const int* __restrict__ batch,
    float* __restrict__ gsum, int* __restrict__ gcnt, int Nn)
{
    const int start = blockIdx.x * 64;
    const int endn = min(start + 64, Nn);
    const int c = threadIdx.x * 4;
    float4 acc = make_float4(0.f, 0.f, 0.f, 0.f);
    int cur = batch[start];
    int runcnt = 0;
    for (int n = start; n < endn; ++n) {
        int g = batch[n];
        if (g != cur) {
            atomicAdd(&gsum[(size_t)cur * 512 + c + 0], acc.x);
            atomicAdd(&gsum[(size_t)cur * 512 + c + 1], acc.y);
            atomicAdd(&gsum[(size_t)cur * 512 + c + 2], acc.z);
            atomicAdd(&gsum[(size_t)cur * 512 + c + 3], acc.w);
            if (threadIdx.x == 0) atomicAdd(&gcnt[cur], runcnt);
            acc = make_float4(0.f, 0.f, 0.f, 0.f);
            runcnt = 0;
            cur = g;
        }
        const float4 v = *(const float4*)(h + (size_t)n * 512 + c);
        acc.x += v.x; acc.y += v.y; acc.z += v.z; acc.w += v.w;
        ++runcnt;
    }
    atomicAdd(&gsum[(size_t)cur * 512 + c + 0], acc.x);
    atomicAdd(&gsum[(size_t)cur * 512 + c + 1], acc.y);
    atomicAdd(&gsum[(size_t)cur * 512 + c + 2], acc.z);
    atomicAdd(&gsum[(size_t)cur * 512 + c + 3], acc.w);
    if (threadIdx.x == 0) atomicAdd(&gcnt[cur], runcnt);
}

// out[g,:] = bl + (gsum[g,:]/max(cnt,1)) @ Wl   (H=512, OUT=8)
__global__ __launch_bounds__(256) void final_kernel(
    const float* __restrict__ gsum, const int* __restrict__ gcnt,
    const float* __restrict__ Wl, const float* __restrict__ bl,
    float* __restrict__ out)
{
    const int g = blockIdx.x;
    const int cnt = gcnt[g];
    const float inv = 1.0f / (float)(cnt > 0 ? cnt : 1);
    float part[8];
#pragma unroll
    for (int o = 0; o < 8; ++o) part[o] = 0.f;
    for (int f = threadIdx.x; f < 512; f += 256) {
        float v = gsum[(size_t)g * 512 + f] * inv;
#pragma unroll
        for (int o = 0; o < 8; ++o) part[o] = fmaf(v, Wl[f * 8 + o], part[o]);
    }
#pragma unroll
    for (int o = 0; o < 8; ++o)
#pragma unroll
        for (int off = 32; off > 0; off >>= 1)
            part[o] += __shfl_down(part[o], off);
    __shared__ float red[4][8];
    const int lane = threadIdx.x & 63;
    const int wid = threadIdx.x >> 6;
    if (lane == 0)
#pragma unroll
        for (int o = 0; o < 8; ++o) red[wid][o] = part[o];
    __syncthreads();
    if (threadIdx.x < 8) {
        const int o = threadIdx.x;
        out[g * 8 + o] = bl[o] + red[0][o] + red[1][o] + red[2][o] + red[3][o];
    }
}

extern "C" void kernel_launch(void* const* d_in, const int* in_sizes, int n_in,
                              void* d_out, int out_size, void* d_ws, size_t ws_size,
                              hipStream_t stream)
{
    const float* x    = (const float*)d_in[0];
    const int*   eidx = (const int*)d_in[1];
    const int*   batch= (const int*)d_in[2];
    const float* ew   = (const float*)d_in[3];
    const float* W1   = (const float*)d_in[4];
    const float* b1   = (const float*)d_in[5];
    const float* W2   = (const float*)d_in[6];
    const float* b2   = (const float*)d_in[7];
    const float* Wl   = (const float*)d_in[8];
    const float* bl   = (const float*)d_in[9];
    float* out = (float*)d_out;

    const int Nn = in_sizes[2];          // 50000
    const int Ee = in_sizes[3];          // 800000
    const int F  = in_sizes[0] / Nn;     // 512
    const int H  = in_sizes[5];          // 512

    const int* src = eidx;
    const int* dst = eidx + Ee;

    // workspace layout (256B-aligned chunks)
    char* base = (char*)d_ws;
    size_t off = 0;
    auto alloc = [&](size_t bytes) -> char* {
        char* p = base + off;
        off += (bytes + 255) & ~(size_t)255;
        return p;
    };
    float* bufA = (float*)alloc((size_t)Nn * H * sizeof(float));   // 102.4 MB
    float* bufB = (float*)alloc((size_t)Nn * H * sizeof(float));   // 102.4 MB
    char* zero_begin = base + off;
    float* deg  = (float*)alloc((size_t)Nn * sizeof(float));       // becomes dinv in-place
    int*   cnt  = (int*)alloc((size_t)Nn * sizeof(int));
    int*   cur  = (int*)alloc((size_t)Nn * sizeof(int));
    float* gsum = (float*)alloc((size_t)64 * 512 * sizeof(float));
    int*   gcnt = (int*)alloc((size_t)64 * sizeof(int));
    char* zero_end = base + off;
    int*   rowptr   = (int*)alloc((size_t)(Nn + 1) * sizeof(int));
    int*   csr_src  = (int*)alloc((size_t)Ee * sizeof(int));
    float* csr_norm = (float*)alloc((size_t)Ee * sizeof(float));
    (void)ws_size;

    // zero the accumulation buffers (harness does not re-poison between replays)
    hipMemsetAsync(zero_begin, 0, (size_t)(zero_end - zero_begin), stream);

    deg_cnt_kernel<<<(Ee + 255) / 256, 256, 0, stream>>>(dst, ew, deg, cnt, Ee);
    dinv_kernel<<<(Nn + 255) / 256, 256, 0, stream>>>(deg, Nn);
    scan_kernel<<<1, 1024, 0, stream>>>(cnt, rowptr, Nn);
    fill_csr_kernel<<<(Ee + 255) / 256, 256, 0, stream>>>(src, dst, ew, deg, rowptr, cur,
                                                          csr_src, csr_norm, Ee);

    dim3 ggrid(H / GEMM_BN, (Nn + GEMM_BM - 1) / GEMM_BM);
    // layer 1
    gemm_f32_kernel<<<ggrid, 256, 0, stream>>>(x, W1, bufA, Nn, H, F);
    agg_kernel<1><<<Nn, 128, 0, stream>>>(bufA, deg, rowptr, csr_src, csr_norm, b1, bufB);
    // layer 2
    gemm_f32_kernel<<<ggrid, 256, 0, stream>>>(bufB, W2, bufA, Nn, H, H);
    agg_kernel<0><<<Nn, 128, 0, stream>>>(bufA, deg, rowptr, csr_src, csr_norm, b2, bufB);
    // pooling + projection
    pool_kernel<<<(Nn + 63) / 64, 128, 0, stream>>>(bufB, batch, gsum, gcnt, Nn);
    final_kernel<<<64, 256, 0, stream>>>(gsum, gcnt, Wl, bl, out);
}

// Round 2
// 549.225 us; speedup vs baseline: 2.5572x; 2.5572x over previous
//
#include <hip/hip_runtime.h>
#include <cstddef>
#include <cstdint>

// ---------------------------------------------------------------------------
// GCN pipeline, bf16 MFMA edition:
//   deg/dinv -> CSR (3-phase scan) -> convert x/W -> MFMA GEMM1 (bf16) ->
//   AGG1(+relu, bf16 out) -> MFMA GEMM2 -> AGG2 (bf16 out) -> pool -> proj
// Sizes: N=50000, E=800000, F=H=512, G=64, OUT=8.
// ---------------------------------------------------------------------------

typedef unsigned short u16;
typedef short s16x8 __attribute__((ext_vector_type(8)));
typedef float f32x4 __attribute__((ext_vector_type(4)));

__device__ __forceinline__ float bf2f(u16 h) {
    union { unsigned int u; float f; } c; c.u = ((unsigned int)h) << 16; return c.f;
}
__device__ __forceinline__ u16 f2bf(float f) {
    union { float f; unsigned int u; } c; c.f = f;
    unsigned int u = c.u;
    u += 0x7FFFu + ((u >> 16) & 1u);   // round-to-nearest-even
    return (u16)(u >> 16);
}

#define GLD_LDS16(g, l) __builtin_amdgcn_global_load_lds( \
    (const __attribute__((address_space(1))) unsigned int*)(const void*)(g), \
    (__attribute__((address_space(3))) unsigned int*)(void*)(l), 16, 0, 0)

// ---------------------------------------------------------------------------
// bf16 MFMA GEMM: C[M,N]=A[M,K]@B[K,N]; A row-major bf16 (M padded to 128),
// Bt = B^T row-major [N][K] bf16, C bf16. 128x128 tile, BK=32, 4 waves.
// ---------------------------------------------------------------------------
#define BM 128
#define BN 128
#define BKK 32

__global__ __launch_bounds__(256) void gemm_bf16_kernel(
    const u16* __restrict__ A, const u16* __restrict__ Bt,
    u16* __restrict__ C, int M, int N, int K)
{
    __shared__ u16 As[BM * BKK];   // [128][32] row-major, 8 KB
    __shared__ u16 Bs[BN * BKK];   // [128][32] row-major, 8 KB
    const int tid = threadIdx.x;
    const int lane = tid & 63;
    const int wave = tid >> 6;
    const int wr = wave >> 1, wc = wave & 1;
    const int m0 = blockIdx.y * BM;
    const int n0 = blockIdx.x * BN;

    // staging geometry: linear 16B-chunk li = i*256+tid; row=li>>2, chunk=(li&3)
    const int srow = tid >> 2;
    const int scol = (tid & 3) * 8;   // bf16 elems

    f32x4 acc[4][4] = {};

    const u16* aptr0 = A + (size_t)(m0 + srow) * K + scol;
    const u16* aptr1 = A + (size_t)(m0 + srow + 64) * K + scol;
    const u16* bptr0 = Bt + (size_t)(n0 + srow) * K + scol;
    const u16* bptr1 = Bt + (size_t)(n0 + srow + 64) * K + scol;

    for (int k0 = 0; k0 < K; k0 += BKK) {
        GLD_LDS16(aptr0 + k0, As + (size_t)tid * 8);
        GLD_LDS16(aptr1 + k0, As + (size_t)(256 + tid) * 8);
        GLD_LDS16(bptr0 + k0, Bs + (size_t)tid * 8);
        GLD_LDS16(bptr1 + k0, Bs + (size_t)(256 + tid) * 8);
        __syncthreads();

        s16x8 af[4], bfr[4];
#pragma unroll
        for (int mi = 0; mi < 4; ++mi)
            af[mi] = *(const s16x8*)(As + (wr * 64 + mi * 16 + (lane & 15)) * BKK + (lane >> 4) * 8);
#pragma unroll
        for (int nj = 0; nj < 4; ++nj)
            bfr[nj] = *(const s16x8*)(Bs + (wc * 64 + nj * 16 + (lane & 15)) * BKK + (lane >> 4) * 8);
#pragma unroll
        for (int mi = 0; mi < 4; ++mi)
#pragma unroll
            for (int nj = 0; nj < 4; ++nj)
                acc[mi][nj] = __builtin_amdgcn_mfma_f32_16x16x32_bf16(af[mi], bfr[nj], acc[mi][nj], 0, 0, 0);
        __syncthreads();
    }

    // C/D layout: col = lane&15, row = (lane>>4)*4 + reg
    const int crow = (lane >> 4) * 4;
    const int ccol = lane & 15;
#pragma unroll
    for (int mi = 0; mi < 4; ++mi) {
        const int gr0 = m0 + wr * 64 + mi * 16 + crow;
#pragma unroll
        for (int r = 0; r < 4; ++r) {
            const int gr = gr0 + r;
            if (gr < M) {
#pragma unroll
                for (int nj = 0; nj < 4; ++nj)
                    C[(size_t)gr * N + n0 + wc * 64 + nj * 16 + ccol] = f2bf(acc[mi][nj][r]);
            }
        }
    }
}

// ---------------------------------------------------------------------------
// setup kernels
// ---------------------------------------------------------------------------
__global__ void deg_cnt_kernel(const int* __restrict__ dst, const float* __restrict__ ew,
                               float* __restrict__ deg, int* __restrict__ cnt, int E)
{
    int e = blockIdx.x * blockDim.x + threadIdx.x;
    if (e >= E) return;
    int d = dst[e];
    atomicAdd(&deg[d], ew[e]);
    atomicAdd(&cnt[d], 1);
}

__global__ void dinv_kernel(float* __restrict__ deg, int Nn)
{
    int i = blockIdx.x * blockDim.x + threadIdx.x;
    if (i >= Nn) return;
    deg[i] = rsqrtf(deg[i] + 1.0f);
}

#define SCAN_BS 1024
__global__ __launch_bounds__(1024) void scan_block_kernel(
    const int* __restrict__ cnt, int* __restrict__ rowptr, int* __restrict__ bsum, int Nn)
{
    __shared__ int tmp[SCAN_BS];
    const int tid = threadIdx.x;
    const int idx = blockIdx.x * SCAN_BS + tid;
    const int v = (idx < Nn) ? cnt[idx] : 0;
    tmp[tid] = v;
    __syncthreads();
    for (int off = 1; off < SCAN_BS; off <<= 1) {
        int y = (tid >= off) ? tmp[tid - off] : 0;
        __syncthreads();
        if (tid >= off) tmp[tid] += y;
        __syncthreads();
    }
    if (idx < Nn) rowptr[idx] = tmp[tid] - v;   // exclusive
    if (tid == SCAN_BS - 1) bsum[blockIdx.x] = tmp[tid];
}

__global__ void scan_sums_kernel(const int* __restrict__ bsum, int* __restrict__ boff,
                                 int nb, int* __restrict__ rowptr, int Nn, int total)
{
    const int tid = threadIdx.x;   // 64 threads, nb <= 64
    const int orig = (tid < nb) ? bsum[tid] : 0;
    int v = orig;
    for (int off = 1; off < 64; off <<= 1) {
        int y = __shfl_up(v, off);
        if (tid >= off) v += y;
    }
    if (tid < nb) boff[tid] = v - orig;   // exclusive
    if (tid == 0) rowptr[Nn] = total;
}

__global__ __launch_bounds__(1024) void scan_add_kernel(
    int* __restrict__ rowptr, const int* __restrict__ boff, int Nn)
{
    const int idx = blockIdx.x * SCAN_BS + threadIdx.x;
    if (idx < Nn) rowptr[idx] += boff[blockIdx.x];
}

__global__ void fill_csr_kernel(const int* __restrict__ src, const int* __restrict__ dst,
                                const float* __restrict__ ew, const float* __restrict__ dinv,
                                const int* __restrict__ rowptr, int* __restrict__ cur,
                                int* __restrict__ csr_src, float* __restrict__ csr_norm, int E)
{
    int e = blockIdx.x * blockDim.x + threadIdx.x;
    if (e >= E) return;
    int s = src[e];
    int d = dst[e];
    float nrm = dinv[s] * ew[e] * dinv[d];
    int p = rowptr[d] + atomicAdd(&cur[d], 1);
    csr_src[p] = s;
    csr_norm[p] = nrm;
}

// ---------------------------------------------------------------------------
// conversion kernels
// ---------------------------------------------------------------------------
__global__ __launch_bounds__(256) void convert_x_kernel(
    const float* __restrict__ x, u16* __restrict__ xb, size_t total4)
{
    size_t i = (size_t)blockIdx.x * blockDim.x + threadIdx.x;
    if (i >= total4) return;
    const float4 v = *(const float4*)(x + i * 4);
    ushort4 o;
    o.x = f2bf(v.x); o.y = f2bf(v.y); o.z = f2bf(v.z); o.w = f2bf(v.w);
    *(ushort4*)(xb + i * 4) = o;
}

// Wt[n][k] = bf16(W[k][n]); grid (N/32, K/32), block 256 (32x8)
__global__ __launch_bounds__(256) void wtrans_kernel(
    const float* __restrict__ W, u16* __restrict__ Wt, int K, int N)
{
    __shared__ float t[32][33];
    const int tx = threadIdx.x & 31;
    const int ty = threadIdx.x >> 5;   // 0..7
    const int nb = blockIdx.x * 32, kb = blockIdx.y * 32;
#pragma unroll
    for (int i = 0; i < 32; i += 8)
        t[ty + i][tx] = W[(size_t)(kb + ty + i) * N + nb + tx];
    __syncthreads();
#pragma unroll
    for (int i = 0; i < 32; i += 8)
        Wt[(size_t)(nb + ty + i) * K + kb + tx] = f2bf(t[tx][ty + i]);
}

// ---------------------------------------------------------------------------
// aggregation: out[n,:] = bias + dinv[n]^2*hw[n,:] + sum_e norm_e*hw[src_e,:]
// hw is bf16 [Mpad][512]; block = 128 threads, 4 cols each. Optional relu.
// ---------------------------------------------------------------------------
template <int RELU>
__global__ __launch_bounds__(128) void agg_kernel(
    const u16* __restrict__ hw, const float* __restrict__ dinv,
    const int* __restrict__ rowptr, const int* __restrict__ csr_src,
    const float* __restrict__ csr_norm, const float* __restrict__ bias,
    u16* __restrict__ outp)
{
    const int n = blockIdx.x;
    const int c = threadIdx.x * 4;
    const float di = dinv[n];
    float4 acc = *(const float4*)(bias + c);
    {
        const float s = di * di;
        const ushort4 hv = *(const ushort4*)(hw + (size_t)n * 512 + c);
        acc.x = fmaf(s, bf2f(hv.x), acc.x);
        acc.y = fmaf(s, bf2f(hv.y), acc.y);
        acc.z = fmaf(s, bf2f(hv.z), acc.z);
        acc.w = fmaf(s, bf2f(hv.w), acc.w);
    }
    const int beg = rowptr[n];
    const int end = rowptr[n + 1];
    for (int i = beg; i < end; ++i) {
        const int s = csr_src[i];
        const float nr = csr_norm[i];
        const ushort4 v = *(const ushort4*)(hw + (size_t)s * 512 + c);
        acc.x = fmaf(nr, bf2f(v.x), acc.x);
        acc.y = fmaf(nr, bf2f(v.y), acc.y);
        acc.z = fmaf(nr, bf2f(v.z), acc.z);
        acc.w = fmaf(nr, bf2f(v.w), acc.w);
    }
    if (RELU) {
        acc.x = fmaxf(acc.x, 0.f);
        acc.y = fmaxf(acc.y, 0.f);
        acc.z = fmaxf(acc.z, 0.f);
        acc.w = fmaxf(acc.w, 0.f);
    }
    ushort4 o;
    o.x = f2bf(acc.x); o.y = f2bf(acc.y); o.z = f2bf(acc.z); o.w = f2bf(acc.w);
    *(ushort4*)(outp + (size_t)n * 512 + c) = o;
}

// ---------------------------------------------------------------------------
// pooling over sorted batch (bf16 input) + final projection
// ---------------------------------------------------------------------------
__global__ __launch_bounds__(128) void pool_kernel(
    const u16* __restrict__ h, const int* __restrict__ batch,
    float* __restrict__ gsum, int* __restrict__ gcnt, int Nn)
{
    const int start = blockIdx.x * 64;
    const int endn = min(start + 64, Nn);
    const int c = threadIdx.x * 4;
    float4 acc = make_float4(0.f, 0.f, 0.f, 0.f);
    int cur = batch[start];
    int runcnt = 0;
    for (int n = start; n < endn; ++n) {
        int g = batch[n];
        if (g != cur) {
            atomicAdd(&gsum[(size_t)cur * 512 + c + 0], acc.x);
            atomicAdd(&gsum[(size_t)cur * 512 + c + 1], acc.y);
            atomicAdd(&gsum[(size_t)cur * 512 + c + 2], acc.z);
            atomicAdd(&gsum[(size_t)cur * 512 + c + 3], acc.w);
            if (threadIdx.x == 0) atomicAdd(&gcnt[cur], runcnt);
            acc = make_float4(0.f, 0.f, 0.f, 0.f);
            runcnt = 0;
            cur = g;
        }
        const ushort4 v = *(const ushort4*)(h + (size_t)n * 512 + c);
        acc.x += bf2f(v.x); acc.y += bf2f(v.y); acc.z += bf2f(v.z); acc.w += bf2f(v.w);
        ++runcnt;
    }
    atomicAdd(&gsum[(size_t)cur * 512 + c + 0], acc.x);
    atomicAdd(&gsum[(size_t)cur * 512 + c + 1], acc.y);
    atomicAdd(&gsum[(size_t)cur * 512 + c + 2], acc.z);
    atomicAdd(&gsum[(size_t)cur * 512 + c + 3], acc.w);
    if (threadIdx.x == 0) atomicAdd(&gcnt[cur], runcnt);
}

__global__ __launch_bounds__(256) void final_kernel(
    const float* __restrict__ gsum, const int* __restrict__ gcnt,
    const float* __restrict__ Wl, const float* __restrict__ bl,
    float* __restrict__ out)
{
    const int g = blockIdx.x;
    const int cnt = gcnt[g];
    const float inv = 1.0f / (float)(cnt > 0 ? cnt : 1);
    float part[8];
#pragma unroll
    for (int o = 0; o < 8; ++o) part[o] = 0.f;
    for (int f = threadIdx.x; f < 512; f += 256) {
        float v = gsum[(size_t)g * 512 + f] * inv;
#pragma unroll
        for (int o = 0; o < 8; ++o) part[o] = fmaf(v, Wl[f * 8 + o], part[o]);
    }
#pragma unroll
    for (int o = 0; o < 8; ++o)
#pragma unroll
        for (int off = 32; off > 0; off >>= 1)
            part[o] += __shfl_down(part[o], off);
    __shared__ float red[4][8];
    const int lane = threadIdx.x & 63;
    const int wid = threadIdx.x >> 6;
    if (lane == 0)
#pragma unroll
        for (int o = 0; o < 8; ++o) red[wid][o] = part[o];
    __syncthreads();
    if (threadIdx.x < 8) {
        const int o = threadIdx.x;
        out[g * 8 + o] = bl[o] + red[0][o] + red[1][o] + red[2][o] + red[3][o];
    }
}

// ---------------------------------------------------------------------------
extern "C" void kernel_launch(void* const* d_in, const int* in_sizes, int n_in,
                              void* d_out, int out_size, void* d_ws, size_t ws_size,
                              hipStream_t stream)
{
    const float* x    = (const float*)d_in[0];
    const int*   eidx = (const int*)d_in[1];
    const int*   batch= (const int*)d_in[2];
    const float* ew   = (const float*)d_in[3];
    const float* W1   = (const float*)d_in[4];
    const float* b1   = (const float*)d_in[5];
    const float* W2   = (const float*)d_in[6];
    const float* b2   = (const float*)d_in[7];
    const float* Wl   = (const float*)d_in[8];
    const float* bl   = (const float*)d_in[9];
    float* out = (float*)d_out;

    const int Nn = in_sizes[2];            // 50000
    const int Ee = in_sizes[3];            // 800000
    const int F  = in_sizes[0] / Nn;       // 512
    const int H  = in_sizes[5];            // 512
    const int Mpad = (Nn + BM - 1) / BM * BM;

    const int* src = eidx;
    const int* dst = eidx + Ee;

    char* base = (char*)d_ws;
    size_t off = 0;
    auto alloc = [&](size_t bytes) -> char* {
        char* p = base + off;
        off += (bytes + 255) & ~(size_t)255;
        return p;
    };
    u16* xb  = (u16*)alloc((size_t)Mpad * F * sizeof(u16));   // 51.2 MB
    u16* hb0 = (u16*)alloc((size_t)Mpad * H * sizeof(u16));   // 51.2 MB
    u16* hb1 = (u16*)alloc((size_t)Mpad * H * sizeof(u16));   // 51.2 MB
    u16* Wt1 = (u16*)alloc((size_t)F * H * sizeof(u16));
    u16* Wt2 = (u16*)alloc((size_t)H * H * sizeof(u16));
    char* zero_begin = base + off;
    float* deg  = (float*)alloc((size_t)Nn * sizeof(float));  // becomes dinv
    int*   cnt  = (int*)alloc((size_t)Nn * sizeof(int));
    int*   cur  = (int*)alloc((size_t)Nn * sizeof(int));
    float* gsum = (float*)alloc((size_t)64 * 512 * sizeof(float));
    int*   gcnt = (int*)alloc((size_t)64 * sizeof(int));
    char* zero_end = base + off;
    int*   rowptr   = (int*)alloc((size_t)(Nn + 1) * sizeof(int));
    int*   bsum     = (int*)alloc(64 * sizeof(int));
    int*   boff     = (int*)alloc(64 * sizeof(int));
    int*   csr_src  = (int*)alloc((size_t)Ee * sizeof(int));
    float* csr_norm = (float*)alloc((size_t)Ee * sizeof(float));
    (void)ws_size;

    hipMemsetAsync(zero_begin, 0, (size_t)(zero_end - zero_begin), stream);

    const int nb = (Nn + SCAN_BS - 1) / SCAN_BS;
    deg_cnt_kernel<<<(Ee + 255) / 256, 256, 0, stream>>>(dst, ew, deg, cnt, Ee);
    dinv_kernel<<<(Nn + 255) / 256, 256, 0, stream>>>(deg, Nn);
    scan_block_kernel<<<nb, SCAN_BS, 0, stream>>>(cnt, rowptr, bsum, Nn);
    scan_sums_kernel<<<1, 64, 0, stream>>>(bsum, boff, nb, rowptr, Nn, Ee);
    scan_add_kernel<<<nb, SCAN_BS, 0, stream>>>(rowptr, boff, Nn);
    fill_csr_kernel<<<(Ee + 255) / 256, 256, 0, stream>>>(src, dst, ew, deg, rowptr, cur,
                                                          csr_src, csr_norm, Ee);

    const size_t total4 = (size_t)Nn * F / 4;
    convert_x_kernel<<<(int)((total4 + 255) / 256), 256, 0, stream>>>(x, xb, total4);
    wtrans_kernel<<<dim3(H / 32, F / 32), 256, 0, stream>>>(W1, Wt1, F, H);
    wtrans_kernel<<<dim3(H / 32, H / 32), 256, 0, stream>>>(W2, Wt2, H, H);

    dim3 ggrid(H / BN, Mpad / BM);
    // layer 1
    gemm_bf16_kernel<<<ggrid, 256, 0, stream>>>(xb, Wt1, hb0, Nn, H, F);
    agg_kernel<1><<<Nn, 128, 0, stream>>>(hb0, deg, rowptr, csr_src, csr_norm, b1, hb1);
    // layer 2
    gemm_bf16_kernel<<<ggrid, 256, 0, stream>>>(hb1, Wt2, hb0, Nn, H, H);
    agg_kernel<0><<<Nn, 128, 0, stream>>>(hb0, deg, rowptr, csr_src, csr_norm, b2, hb1);
    // pooling + projection
    pool_kernel<<<(Nn + 63) / 64, 128, 0, stream>>>(hb1, batch, gsum, gcnt, Nn);
    final_kernel<<<64, 256, 0, stream>>>(gsum, gcnt, Wl, bl, out);
}